// Round 8
// baseline (232.075 us; speedup 1.0000x reference)
//
#include <hip/hip_runtime.h>
#include <cstddef>

// Voxel encoder: B=2, N=16384, G=512 voxels x K=32 pts, d=128, S=2 layers.
// Round 8: mega-kernel widened to 512 threads (8 waves/voxel, 16 waves/CU at
// 2 blocks/CU) and PV moved to MFMA (softmax emits bf16 P; phase A writes V
// transposed vT[f][j] with b64 stores so PV B-frags are b128 reads).

#define D_   128
#define VSF  0.25f
#define QSF  0.01f
#define LQ   50
#define G_   512
#define KP   32
#define BB   2
#define NP   16384
#define MT   32768
#define SCALE 0.08838834764831845f   // 1/sqrt(128)
#define NT_ALL 34           // 24 qkv tiles + 10 dk tiles (cols 0..543)
#define FRAG_S (NT_ALL * 4 * 64 * 8)   // ushorts per layer frag buffer

using short8 = __attribute__((ext_vector_type(8))) short;
using f32x4  = __attribute__((ext_vector_type(4))) float;

__device__ inline unsigned short f2bf(float x) {
  unsigned u = __builtin_bit_cast(unsigned, x);
  u += 0x7fffu + ((u >> 16) & 1u);      // round-to-nearest-even
  return (unsigned short)(u >> 16);
}
__device__ inline float bu(unsigned short h) {
  return __builtin_bit_cast(float, (unsigned)h << 16);
}
__device__ inline short8 as_short8(uint4 v) {
  union { uint4 u; short8 s; } x; x.u = v; return x.s;
}

// ---------------------------------------------------------------------------
// Transpose the (s,1) table slices into Tt[s][e=128][c=256], c = axis*50+l,
// zero-padded for c in [150,256). grid = 256 (s*128+e), block = 256 (c).
// ---------------------------------------------------------------------------
__global__ __launch_bounds__(256) void prep_tt(
    const float* __restrict__ tbl_x, const float* __restrict__ tbl_y,
    const float* __restrict__ tbl_z, float* __restrict__ Tt)
{
  const int c = threadIdx.x;
  const int s = blockIdx.x >> 7;
  const int e = blockIdx.x & 127;
  float v = 0.f;
  if (c < 150) {
    const int axis = c / 50, l = c - axis * 50;
    const float* tb = (axis == 0 ? tbl_x : (axis == 1 ? tbl_y : tbl_z));
    v = tb[(((size_t)s * 3 + 1) * LQ + l) * D_ + e];
  }
  Tt[((size_t)(s * 128 + e)) * 256 + c] = v;
}

// ---------------------------------------------------------------------------
// Wf = Wk @ Tt (fp32, both layers). grid=(2,2,2): x=m-tile, y=n-tile, z=s.
// ---------------------------------------------------------------------------
__global__ __launch_bounds__(256) void wf_gemm(
    const float* __restrict__ qkv_w, const float* __restrict__ Tt,
    float* __restrict__ Wf)
{
  __shared__ __align__(16) float A_s[16][68];
  __shared__ __align__(16) float B_s[16][132];
  const int t  = threadIdx.x;
  const int s  = blockIdx.z;
  const float* A = qkv_w + (size_t)s * 128 * 384 + 128;   // Wk rows, lda=384
  const float* B = Tt + (size_t)s * 128 * 256;
  float* C       = Wf + (size_t)s * 128 * 256;
  const int m0 = blockIdx.x * 64;
  const int n0 = blockIdx.y * 128;
  const int r  = t >> 2;
  const int kq = (t & 3) * 4;
  const float* arow = A + (size_t)(m0 + r) * 384;
  const int kkb = t >> 4;
  const int cb  = (t & 15) * 8;
  const float* wbase = B + (size_t)kkb * 256 + n0 + cb;
  const int tx = t & 31, ty = t >> 5;

  float acc[8][4];
  #pragma unroll
  for (int i = 0; i < 8; i++)
    #pragma unroll
    for (int j = 0; j < 4; j++) acc[i][j] = 0.f;

  for (int k0 = 0; k0 < 128; k0 += 16) {
    float4 av = *(const float4*)(arow + k0 + kq);
    float4 b0 = *(const float4*)(wbase + (size_t)k0 * 256);
    float4 b1 = *(const float4*)(wbase + (size_t)k0 * 256 + 4);
    __syncthreads();
    A_s[kq + 0][r] = av.x;
    A_s[kq + 1][r] = av.y;
    A_s[kq + 2][r] = av.z;
    A_s[kq + 3][r] = av.w;
    *(float4*)&B_s[kkb][cb]     = b0;
    *(float4*)&B_s[kkb][cb + 4] = b1;
    __syncthreads();
    #pragma unroll
    for (int kk = 0; kk < 16; kk++) {
      float4 a03 = *(const float4*)&A_s[kk][ty * 8];
      float4 a47 = *(const float4*)&A_s[kk][ty * 8 + 4];
      float4 bv  = *(const float4*)&B_s[kk][tx * 4];
      float a[8] = {a03.x, a03.y, a03.z, a03.w, a47.x, a47.y, a47.z, a47.w};
      float bj[4] = {bv.x, bv.y, bv.z, bv.w};
      #pragma unroll
      for (int i = 0; i < 8; i++)
        #pragma unroll
        for (int j = 0; j < 4; j++)
          acc[i][j] += a[i] * bj[j];
    }
  }
  #pragma unroll
  for (int i = 0; i < 8; i++) {
    float4 o = {acc[i][0], acc[i][1], acc[i][2], acc[i][3]};
    *(float4*)(C + (size_t)(m0 + ty * 8 + i) * 256 + n0 + tx * 4) = o;
  }
}

// ---------------------------------------------------------------------------
// pack2: all fragment packing + combined bias in one launch. 370 blocks x 64.
// ---------------------------------------------------------------------------
__global__ __launch_bounds__(64) void pack2(
    const float* __restrict__ qkv_w, const float* __restrict__ Wf,
    const float* __restrict__ trans_w, const float* __restrict__ qkv_b,
    const float* __restrict__ Tt,
    unsigned short* __restrict__ allfrag,
    unsigned short* __restrict__ transfrag,
    float* __restrict__ bc)
{
  const int blk = blockIdx.x;
  const int lane = threadIdx.x;
  const float* B; int ldb, dstidx; unsigned short* dst; int kbase, n;
  if (blk < 192) {
    const int s = blk / 96, r = blk - s * 96;
    const int nt = r >> 2, ks = r & 3;
    B = qkv_w + (size_t)s * 128 * 384; ldb = 384;
    n = nt * 16 + (lane & 15);
    kbase = ks * 32 + ((lane >> 4) * 8);
    dst = allfrag + (size_t)s * FRAG_S;
    dstidx = nt * 4 + ks;
  } else if (blk < 272) {
    const int s = (blk - 192) / 40, r = (blk - 192) - s * 40;
    const int snt = r >> 2, ks = r & 3;
    B = Wf + (size_t)s * 32768; ldb = 256;
    n = snt * 16 + (lane & 15);
    kbase = ks * 32 + ((lane >> 4) * 8);
    dst = allfrag + (size_t)s * FRAG_S;
    dstidx = (24 + snt) * 4 + ks;
  } else if (blk < 368) {
    const int r = blk - 272;
    const int nt = r / 12, ks = r - nt * 12;
    B = trans_w; ldb = 128;
    n = nt * 16 + (lane & 15);
    kbase = ks * 32 + ((lane >> 4) * 8);
    dst = transfrag;
    dstidx = nt * 12 + ks;
  } else {
    const int s = blk - 368;
    for (int c = lane; c < 544; c += 64) {
      float v;
      if (c < 384) {
        v = qkv_b[s * 384 + c];
      } else {
        const float* bk = qkv_b + (size_t)s * 384 + 128;
        const float* T  = Tt + (size_t)s * 128 * 256 + (c - 384);
        float a = 0.f;
        #pragma unroll 4
        for (int e = 0; e < 128; e++) a += bk[e] * T[(size_t)e * 256];
        v = a;
      }
      bc[s * 544 + c] = v;
    }
    return;
  }
  unsigned v[4];
  #pragma unroll
  for (int h = 0; h < 4; h++) {
    const float x0 = B[(size_t)(kbase + 2 * h) * ldb + n];
    const float x1 = B[(size_t)(kbase + 2 * h + 1) * ldb + n];
    v[h] = f2bf(x0) | ((unsigned)f2bf(x1) << 16);
  }
  uint4 o = {v[0], v[1], v[2], v[3]};
  *(uint4*)(dst + ((size_t)dstidx * 64 + lane) * 8) = o;
}

// ---------------------------------------------------------------------------
// MEGA: one block (8 waves, 512 threads) per voxel; whole network per voxel.
// LDS ~63KB -> 2 blocks/CU -> 16 waves/CU. grid = 1024.
// qk_s row layout: q 0:128 (later f2) | k 128:256 | dk 256:406; stride 424.
// ---------------------------------------------------------------------------
__global__ __launch_bounds__(512, 4) void mega(
    const float* __restrict__ inputs,
    const float* __restrict__ coords,
    const int*   __restrict__ groups,
    const unsigned short* __restrict__ allfrag,   // 2 x FRAG_S
    const float* __restrict__ bc,                 // 2 x 544
    const unsigned short* __restrict__ transfrag, // 8 nt x 12 ks
    const float* __restrict__ trans_b, const float* __restrict__ ln_g,
    const float* __restrict__ ln_b,
    float* __restrict__ out_all)
{
  __shared__ __align__(16) unsigned short feats_s[32][136];
  __shared__ __align__(16) unsigned short f1_s[32][136];
  __shared__ __align__(16) unsigned short qk_s[32][424];   // q|k|dk; f2->q
  __shared__ __align__(16) unsigned short vT_s[128][40];   // V^T [f][j]
  __shared__ __align__(16) unsigned short p_s[32][40];     // bf16 attn P
  __shared__ float sc_s[32 * 33];
  __shared__ float cs[32][4];
  __shared__ float red_s[8][16][2];
  __shared__ float wmax_s[2][128];
  __shared__ float pooled_s[128];

  const int t   = threadIdx.x;
  const int bid = blockIdx.x;
  const int b   = bid >> 9;
  const int g   = bid & 511;
  const int wv = t >> 6, lane = t & 63, quad = lane >> 4, col = lane & 15;

  // ---- stage feats (gather + fp32->bf16): 16 thr/row, 8 elems each ----
  {
    const int p = t >> 4, sg = t & 15;
    const int pid = groups[(b << 14) + g * KP + p];
    const float* src = inputs + ((size_t)(b << 14) + (size_t)pid) * D_ + sg * 8;
    float4 a0 = *(const float4*)(src);
    float4 a1 = *(const float4*)(src + 4);
    uint4 o0;
    o0.x = f2bf(a0.x) | ((unsigned)f2bf(a0.y) << 16);
    o0.y = f2bf(a0.z) | ((unsigned)f2bf(a0.w) << 16);
    o0.z = f2bf(a1.x) | ((unsigned)f2bf(a1.y) << 16);
    o0.w = f2bf(a1.z) | ((unsigned)f2bf(a1.w) << 16);
    *(uint4*)&feats_s[p][sg * 8] = o0;
  }
  if (t < 32) {
    const int pid = groups[(b << 14) + g * KP + t];
    const float* cp = coords + ((size_t)(b << 14) + (size_t)pid) * 3;
    cs[t][0] = cp[0]; cs[t][1] = cp[1]; cs[t][2] = cp[2];
  }
  __syncthreads();

  // ---- per-wave tile assignment for phase A (8 waves) ----
  const int starts[4] = {0, 9, 18, 26};
  const int range = wv >> 1;            // 4 tile ranges
  const int rt    = wv & 1;             // row half (rows rt*16..rt*16+15)
  const int start = starts[range];
  const int cnt   = (range < 2) ? 9 : 8;

  for (int layer = 0; layer < 2; layer++) {
    const unsigned short (*Asrc)[136] = (layer == 0) ? feats_s : f1_s;
    const uint4* fr = (const uint4*)(allfrag + (size_t)layer * FRAG_S) + lane;
    const float* bcl = bc + layer * 544;

    // Phase A: qkv+dk GEMM (16 rows x ~144 cols per wave, K=128)
    f32x4 acc[9];
    #pragma unroll
    for (int u = 0; u < 9; u++) acc[u] = (f32x4){0.f, 0.f, 0.f, 0.f};
    #pragma unroll
    for (int ks = 0; ks < 4; ks++) {
      short8 av = as_short8(*(const uint4*)&Asrc[rt * 16 + col][ks * 32 + quad * 8]);
      #pragma unroll
      for (int u = 0; u < 9; u++) {
        if (u < cnt) {
          short8 bv = as_short8(fr[((start + u) * 4 + ks) * 64]);
          acc[u] = __builtin_amdgcn_mfma_f32_16x16x32_bf16(av, bv, acc[u], 0, 0, 0);
        }
      }
    }
    // epilogue: +bias -> LDS. q/k/dk scalar b16; V transposed b64.
    #pragma unroll
    for (int u = 0; u < 9; u++) {
      if (u < cnt) {
        const int cc = (start + u) * 16 + col;
        const float bsv = bcl[cc];
        if (cc >= 256 && cc < 384) {          // V tile -> vT_s[f][j], b64
          const unsigned lo = f2bf(acc[u][0] + bsv)
                            | ((unsigned)f2bf(acc[u][1] + bsv) << 16);
          const unsigned hi = f2bf(acc[u][2] + bsv)
                            | ((unsigned)f2bf(acc[u][3] + bsv) << 16);
          uint2 w = {lo, hi};
          *(uint2*)&vT_s[cc - 256][rt * 16 + quad * 4] = w;
        } else {
          const int ccol = (cc < 256) ? cc : cc - 128;   // dk -> 256..405
          #pragma unroll
          for (int reg = 0; reg < 4; reg++)
            qk_s[rt * 16 + quad * 4 + reg][ccol] = f2bf(acc[u][reg] + bsv);
        }
      }
    }
    __syncthreads();

    // scores via MFMA from LDS frags (waves 0..3)
    if (wv < 4) {
      const int ihalf = wv >> 1, jhalf = wv & 1;
      f32x4 sacc = {0.f, 0.f, 0.f, 0.f};
      #pragma unroll
      for (int ks = 0; ks < 4; ks++) {
        short8 qv = as_short8(*(const uint4*)&qk_s[ihalf * 16 + col][ks * 32 + quad * 8]);
        short8 kv = as_short8(*(const uint4*)&qk_s[jhalf * 16 + col][128 + ks * 32 + quad * 8]);
        sacc = __builtin_amdgcn_mfma_f32_16x16x32_bf16(qv, kv, sacc, 0, 0, 0);
      }
      const int j = jhalf * 16 + col;
      const float cjx = cs[j][0], cjy = cs[j][1], cjz = cs[j][2];
      #pragma unroll
      for (int reg = 0; reg < 4; reg++) {
        const int i = ihalf * 16 + quad * 4 + reg;
        const float dx = cs[i][0] - cjx;
        const float dy = cs[i][1] - cjy;
        const float dz = cs[i][2] - cjz;
        int ix = (int)floorf((dx + VSF) / QSF);
        int iy = (int)floorf((dy + VSF) / QSF);
        int iz = (int)floorf((dz + VSF) / QSF);
        ix = ix < 0 ? 0 : (ix > 49 ? 49 : ix);
        iy = iy < 0 ? 0 : (iy > 49 ? 49 : iy);
        iz = iz < 0 ? 0 : (iz > 49 ? 49 : iz);
        const unsigned short* dki = &qk_s[i][256];
        const float biasv = bu(dki[ix]) + bu(dki[50 + iy]) + bu(dki[100 + iz]);
        sc_s[i * 33 + j] = (sacc[reg] + biasv) * SCALE;
      }
    }
    __syncthreads();

    // softmax: 8 threads per row (t<256); emit bf16 P
    if (t < 256) {
      const int p = t >> 3, sg = t & 7;
      float vals[4];
      float lm = -1e30f;
      #pragma unroll
      for (int u = 0; u < 4; u++) {
        vals[u] = sc_s[p * 33 + sg + u * 8];
        lm = fmaxf(lm, vals[u]);
      }
      lm = fmaxf(lm, __shfl_xor(lm, 1));
      lm = fmaxf(lm, __shfl_xor(lm, 2));
      lm = fmaxf(lm, __shfl_xor(lm, 4));
      float ls = 0.f;
      #pragma unroll
      for (int u = 0; u < 4; u++) { vals[u] = __expf(vals[u] - lm); ls += vals[u]; }
      ls += __shfl_xor(ls, 1);
      ls += __shfl_xor(ls, 2);
      ls += __shfl_xor(ls, 4);
      const float inv = 1.f / ls;
      #pragma unroll
      for (int u = 0; u < 4; u++)
        p_s[p][sg + u * 8] = f2bf(vals[u] * inv);
    }
    __syncthreads();

    // PV via MFMA: wave wv does mt=wv&1, ftiles (wv>>1)*2 + {0,1}
    {
      const int mt = wv & 1, ftb = (wv >> 1) * 2;
      unsigned short* dst_base = (layer == 0) ? &f1_s[0][0] : &qk_s[0][0];
      const int dst_ld = (layer == 0) ? 136 : 424;
      #pragma unroll
      for (int u = 0; u < 2; u++) {
        const int ft = ftb + u;
        short8 pv = as_short8(*(const uint4*)&p_s[mt * 16 + col][quad * 8]);
        short8 vv = as_short8(*(const uint4*)&vT_s[ft * 16 + col][quad * 8]);
        f32x4 o = (f32x4){0.f, 0.f, 0.f, 0.f};
        o = __builtin_amdgcn_mfma_f32_16x16x32_bf16(pv, vv, o, 0, 0, 0);
        const int f = ft * 16 + col;
        #pragma unroll
        for (int reg = 0; reg < 4; reg++) {
          const int i = mt * 16 + quad * 4 + reg;
          dst_base[i * dst_ld + f] = f2bf(o[reg]);
        }
      }
    }
    __syncthreads();
  }

  // ---- trans GEMM (K=384: feats|f1|f2) + LN + ReLU + maxpool + outputs ----
  const int mtile = wv & 1, colq = wv >> 1;   // 2 ntiles per wave
  f32x4 tacc[2];
  tacc[0] = (f32x4){0.f, 0.f, 0.f, 0.f};
  tacc[1] = (f32x4){0.f, 0.f, 0.f, 0.f};
  const uint4* tf = (const uint4*)transfrag + lane;
  #pragma unroll
  for (int ks = 0; ks < 12; ks++) {
    const unsigned short* ar =
        (ks < 4) ? &feats_s[mtile * 16 + col][(ks & 3) * 32 + quad * 8]
      : (ks < 8) ? &f1_s[mtile * 16 + col][(ks & 3) * 32 + quad * 8]
                 : &qk_s[mtile * 16 + col][(ks & 3) * 32 + quad * 8];  // f2
    short8 av = as_short8(*(const uint4*)ar);
    #pragma unroll
    for (int u = 0; u < 2; u++) {
      const int nt = colq * 2 + u;
      short8 bv = as_short8(tf[(nt * 12 + ks) * 64]);
      tacc[u] = __builtin_amdgcn_mfma_f32_16x16x32_bf16(av, bv, tacc[u], 0, 0, 0);
    }
  }
  // bias + LN partial stats (32 cols per wave)
  float s[4] = {0.f, 0.f, 0.f, 0.f}, ssq[4] = {0.f, 0.f, 0.f, 0.f};
  float gg[2], lb[2];
  #pragma unroll
  for (int u = 0; u < 2; u++) {
    const int c = (colq * 2 + u) * 16 + col;
    const float bsv = trans_b[c];
    gg[u] = ln_g[c]; lb[u] = ln_b[c];
    #pragma unroll
    for (int reg = 0; reg < 4; reg++) {
      const float v = tacc[u][reg] + bsv;
      tacc[u][reg] = v;
      s[reg] += v; ssq[reg] += v * v;
    }
  }
  #pragma unroll
  for (int mk = 1; mk <= 8; mk <<= 1) {
    #pragma unroll
    for (int reg = 0; reg < 4; reg++) {
      s[reg]   += __shfl_xor(s[reg],   mk);
      ssq[reg] += __shfl_xor(ssq[reg], mk);
    }
  }
  if (col == 0) {
    #pragma unroll
    for (int reg = 0; reg < 4; reg++) {
      red_s[wv][quad * 4 + reg][0] = s[reg];
      red_s[wv][quad * 4 + reg][1] = ssq[reg];
    }
  }
  __syncthreads();
  float mu[4], rstd[4];
  #pragma unroll
  for (int reg = 0; reg < 4; reg++) {
    float st = 0.f, sst = 0.f;
    #pragma unroll
    for (int w = 0; w < 4; w++) {
      st  += red_s[mtile + w * 2][quad * 4 + reg][0];
      sst += red_s[mtile + w * 2][quad * 4 + reg][1];
    }
    mu[reg] = st * (1.f / 128.f);
    const float var = sst * (1.f / 128.f) - mu[reg] * mu[reg];
    rstd[reg] = rsqrtf(var + 1e-5f);
  }
  // LN + ReLU + column max over this wave's 16 rows
  float cm[2];
  #pragma unroll
  for (int u = 0; u < 2; u++) {
    float mx = 0.f;   // ReLU floor
    #pragma unroll
    for (int reg = 0; reg < 4; reg++) {
      float v = (tacc[u][reg] - mu[reg]) * rstd[reg] * gg[u] + lb[u];
      v = fmaxf(v, 0.f);
      mx = fmaxf(mx, v);
    }
    cm[u] = mx;
  }
  #pragma unroll
  for (int u = 0; u < 2; u++) {
    cm[u] = fmaxf(cm[u], __shfl_xor(cm[u], 16));
    cm[u] = fmaxf(cm[u], __shfl_xor(cm[u], 32));
  }
  if (quad == 0) {
    #pragma unroll
    for (int u = 0; u < 2; u++)
      wmax_s[mtile][(colq * 2 + u) * 16 + col] = cm[u];
  }
  __syncthreads();

  // pooled = max over both row halves; grid-reordered out write
  if (t < 128) {
    const int c = t;
    const float mx = fmaxf(wmax_s[0][c], wmax_s[1][c]);
    pooled_s[c] = mx;
    const int mm = g >> 6, nn = (g >> 3) & 7, tt2 = g & 7;
    const int opos = tt2 * 64 + nn * 8 + mm;
    out_all[((size_t)b * G_ + opos) * D_ + c] = mx;
  }
  __syncthreads();

  // scatter pooled to every point (for_ret); 256 threads, 16 floats each
  if (t < 256) {
    const int p = t >> 3, sg = t & 7;
    const int pid = groups[(b << 14) + g * KP + p];
    float* dst = out_all + (size_t)BB * G_ * D_
               + ((size_t)(b << 14) + (size_t)pid) * D_ + sg * 16;
    #pragma unroll
    for (int u = 0; u < 4; u++)
      *(float4*)(dst + u * 4) = *(const float4*)&pooled_s[sg * 16 + u * 4];
  }
}

// ---------------------------------------------------------------------------
extern "C" void kernel_launch(void* const* d_in, const int* in_sizes, int n_in,
                              void* d_out, int out_size, void* d_ws, size_t ws_size,
                              hipStream_t stream) {
  const float* inputs  = (const float*)d_in[0];
  const float* coords  = (const float*)d_in[1];
  const float* qkv_w   = (const float*)d_in[2];   // [2,128,384]
  const float* qkv_b   = (const float*)d_in[3];   // [2,384]
  const float* tbl_x   = (const float*)d_in[4];   // [2,3,50,128]
  const float* tbl_y   = (const float*)d_in[5];
  const float* tbl_z   = (const float*)d_in[6];
  const float* trans_w = (const float*)d_in[7];   // [384,128]
  const float* trans_b = (const float*)d_in[8];
  const float* ln_g    = (const float*)d_in[9];
  const float* ln_b    = (const float*)d_in[10];
  const int*   groups  = (const int*)d_in[11];    // [2,512,32] flat

  float* out = (float*)d_out;
  unsigned short* allfrag   = (unsigned short*)d_ws;       // 2*FRAG_S
  unsigned short* transfrag = allfrag + 2 * FRAG_S;        // 96*512
  float* Tt  = (float*)(transfrag + 96 * 512);             // 2*128*256 f32
  float* Wf  = Tt + (size_t)2 * 128 * 256;                 // 2*128*256 f32
  float* bc  = Wf + (size_t)2 * 128 * 256;                 // 2*544 f32

  // ---- prep (weights only) ----
  prep_tt<<<256, 256, 0, stream>>>(tbl_x, tbl_y, tbl_z, Tt);
  wf_gemm<<<dim3(2, 2, 2), 256, 0, stream>>>(qkv_w, Tt, Wf);
  pack2<<<370, 64, 0, stream>>>(qkv_w, Wf, trans_w, qkv_b, Tt,
                                allfrag, transfrag, bc);

  // ---- whole network, one kernel ----
  mega<<<BB * G_, 512, 0, stream>>>(inputs, coords, groups, allfrag, bc,
                                    transfrag, trans_b, ln_g, ln_b, out);
}

// Round 9
// 188.728 us; speedup vs baseline: 1.2297x; 1.2297x over previous
//
#include <hip/hip_runtime.h>
#include <cstddef>

// Voxel encoder: B=2, N=16384, G=512 voxels x K=32 pts, d=128, S=2 layers.
// Round 9: round-8 structure (512 thr, 8 waves/voxel, PV via MFMA with
// transposed V) with the spill bug fixed: __launch_bounds__(512,2) (r8's
// (512,4) capped VGPRs at 64 -> 210MB/dispatch scratch traffic) and phase A
// restructured to tile-pairs with preloaded A-frags (worst-case ~50 live
// VGPRs instead of a 9-acc array held across the K-loop).

#define D_   128
#define VSF  0.25f
#define QSF  0.01f
#define LQ   50
#define G_   512
#define KP   32
#define BB   2
#define NP   16384
#define MT   32768
#define SCALE 0.08838834764831845f   // 1/sqrt(128)
#define NT_ALL 34           // 24 qkv tiles + 10 dk tiles (cols 0..543)
#define FRAG_S (NT_ALL * 4 * 64 * 8)   // ushorts per layer frag buffer

using short8 = __attribute__((ext_vector_type(8))) short;
using f32x4  = __attribute__((ext_vector_type(4))) float;

__device__ inline unsigned short f2bf(float x) {
  unsigned u = __builtin_bit_cast(unsigned, x);
  u += 0x7fffu + ((u >> 16) & 1u);      // round-to-nearest-even
  return (unsigned short)(u >> 16);
}
__device__ inline float bu(unsigned short h) {
  return __builtin_bit_cast(float, (unsigned)h << 16);
}
__device__ inline short8 as_short8(uint4 v) {
  union { uint4 u; short8 s; } x; x.u = v; return x.s;
}

// ---------------------------------------------------------------------------
// Transpose the (s,1) table slices into Tt[s][e=128][c=256], c = axis*50+l,
// zero-padded for c in [150,256). grid = 256 (s*128+e), block = 256 (c).
// ---------------------------------------------------------------------------
__global__ __launch_bounds__(256) void prep_tt(
    const float* __restrict__ tbl_x, const float* __restrict__ tbl_y,
    const float* __restrict__ tbl_z, float* __restrict__ Tt)
{
  const int c = threadIdx.x;
  const int s = blockIdx.x >> 7;
  const int e = blockIdx.x & 127;
  float v = 0.f;
  if (c < 150) {
    const int axis = c / 50, l = c - axis * 50;
    const float* tb = (axis == 0 ? tbl_x : (axis == 1 ? tbl_y : tbl_z));
    v = tb[(((size_t)s * 3 + 1) * LQ + l) * D_ + e];
  }
  Tt[((size_t)(s * 128 + e)) * 256 + c] = v;
}

// ---------------------------------------------------------------------------
// Wf = Wk @ Tt (fp32, both layers). grid=(2,2,2): x=m-tile, y=n-tile, z=s.
// ---------------------------------------------------------------------------
__global__ __launch_bounds__(256) void wf_gemm(
    const float* __restrict__ qkv_w, const float* __restrict__ Tt,
    float* __restrict__ Wf)
{
  __shared__ __align__(16) float A_s[16][68];
  __shared__ __align__(16) float B_s[16][132];
  const int t  = threadIdx.x;
  const int s  = blockIdx.z;
  const float* A = qkv_w + (size_t)s * 128 * 384 + 128;   // Wk rows, lda=384
  const float* B = Tt + (size_t)s * 128 * 256;
  float* C       = Wf + (size_t)s * 128 * 256;
  const int m0 = blockIdx.x * 64;
  const int n0 = blockIdx.y * 128;
  const int r  = t >> 2;
  const int kq = (t & 3) * 4;
  const float* arow = A + (size_t)(m0 + r) * 384;
  const int kkb = t >> 4;
  const int cb  = (t & 15) * 8;
  const float* wbase = B + (size_t)kkb * 256 + n0 + cb;
  const int tx = t & 31, ty = t >> 5;

  float acc[8][4];
  #pragma unroll
  for (int i = 0; i < 8; i++)
    #pragma unroll
    for (int j = 0; j < 4; j++) acc[i][j] = 0.f;

  for (int k0 = 0; k0 < 128; k0 += 16) {
    float4 av = *(const float4*)(arow + k0 + kq);
    float4 b0 = *(const float4*)(wbase + (size_t)k0 * 256);
    float4 b1 = *(const float4*)(wbase + (size_t)k0 * 256 + 4);
    __syncthreads();
    A_s[kq + 0][r] = av.x;
    A_s[kq + 1][r] = av.y;
    A_s[kq + 2][r] = av.z;
    A_s[kq + 3][r] = av.w;
    *(float4*)&B_s[kkb][cb]     = b0;
    *(float4*)&B_s[kkb][cb + 4] = b1;
    __syncthreads();
    #pragma unroll
    for (int kk = 0; kk < 16; kk++) {
      float4 a03 = *(const float4*)&A_s[kk][ty * 8];
      float4 a47 = *(const float4*)&A_s[kk][ty * 8 + 4];
      float4 bv  = *(const float4*)&B_s[kk][tx * 4];
      float a[8] = {a03.x, a03.y, a03.z, a03.w, a47.x, a47.y, a47.z, a47.w};
      float bj[4] = {bv.x, bv.y, bv.z, bv.w};
      #pragma unroll
      for (int i = 0; i < 8; i++)
        #pragma unroll
        for (int j = 0; j < 4; j++)
          acc[i][j] += a[i] * bj[j];
    }
  }
  #pragma unroll
  for (int i = 0; i < 8; i++) {
    float4 o = {acc[i][0], acc[i][1], acc[i][2], acc[i][3]};
    *(float4*)(C + (size_t)(m0 + ty * 8 + i) * 256 + n0 + tx * 4) = o;
  }
}

// ---------------------------------------------------------------------------
// pack2: all fragment packing + combined bias in one launch. 370 blocks x 64.
// ---------------------------------------------------------------------------
__global__ __launch_bounds__(64) void pack2(
    const float* __restrict__ qkv_w, const float* __restrict__ Wf,
    const float* __restrict__ trans_w, const float* __restrict__ qkv_b,
    const float* __restrict__ Tt,
    unsigned short* __restrict__ allfrag,
    unsigned short* __restrict__ transfrag,
    float* __restrict__ bc)
{
  const int blk = blockIdx.x;
  const int lane = threadIdx.x;
  const float* B; int ldb, dstidx; unsigned short* dst; int kbase, n;
  if (blk < 192) {
    const int s = blk / 96, r = blk - s * 96;
    const int nt = r >> 2, ks = r & 3;
    B = qkv_w + (size_t)s * 128 * 384; ldb = 384;
    n = nt * 16 + (lane & 15);
    kbase = ks * 32 + ((lane >> 4) * 8);
    dst = allfrag + (size_t)s * FRAG_S;
    dstidx = nt * 4 + ks;
  } else if (blk < 272) {
    const int s = (blk - 192) / 40, r = (blk - 192) - s * 40;
    const int snt = r >> 2, ks = r & 3;
    B = Wf + (size_t)s * 32768; ldb = 256;
    n = snt * 16 + (lane & 15);
    kbase = ks * 32 + ((lane >> 4) * 8);
    dst = allfrag + (size_t)s * FRAG_S;
    dstidx = (24 + snt) * 4 + ks;
  } else if (blk < 368) {
    const int r = blk - 272;
    const int nt = r / 12, ks = r - nt * 12;
    B = trans_w; ldb = 128;
    n = nt * 16 + (lane & 15);
    kbase = ks * 32 + ((lane >> 4) * 8);
    dst = transfrag;
    dstidx = nt * 12 + ks;
  } else {
    const int s = blk - 368;
    for (int c = lane; c < 544; c += 64) {
      float v;
      if (c < 384) {
        v = qkv_b[s * 384 + c];
      } else {
        const float* bk = qkv_b + (size_t)s * 384 + 128;
        const float* T  = Tt + (size_t)s * 128 * 256 + (c - 384);
        float a = 0.f;
        #pragma unroll 4
        for (int e = 0; e < 128; e++) a += bk[e] * T[(size_t)e * 256];
        v = a;
      }
      bc[s * 544 + c] = v;
    }
    return;
  }
  unsigned v[4];
  #pragma unroll
  for (int h = 0; h < 4; h++) {
    const float x0 = B[(size_t)(kbase + 2 * h) * ldb + n];
    const float x1 = B[(size_t)(kbase + 2 * h + 1) * ldb + n];
    v[h] = f2bf(x0) | ((unsigned)f2bf(x1) << 16);
  }
  uint4 o = {v[0], v[1], v[2], v[3]};
  *(uint4*)(dst + ((size_t)dstidx * 64 + lane) * 8) = o;
}

// ---------------------------------------------------------------------------
// MEGA: one block (8 waves, 512 threads) per voxel; whole network per voxel.
// LDS ~63KB -> 2 blocks/CU -> 16 waves/CU. grid = 1024.
// qk_s row layout: q 0:128 (later f2) | k 128:256 | dk 256:406; stride 424.
// __launch_bounds__(512,2): VGPR cap 256 (r8's (512,4) -> 64 VGPR -> spills).
// ---------------------------------------------------------------------------
__global__ __launch_bounds__(512, 2) void mega(
    const float* __restrict__ inputs,
    const float* __restrict__ coords,
    const int*   __restrict__ groups,
    const unsigned short* __restrict__ allfrag,   // 2 x FRAG_S
    const float* __restrict__ bc,                 // 2 x 544
    const unsigned short* __restrict__ transfrag, // 8 nt x 12 ks
    const float* __restrict__ trans_b, const float* __restrict__ ln_g,
    const float* __restrict__ ln_b,
    float* __restrict__ out_all)
{
  __shared__ __align__(16) unsigned short feats_s[32][136];
  __shared__ __align__(16) unsigned short f1_s[32][136];
  __shared__ __align__(16) unsigned short qk_s[32][424];   // q|k|dk; f2->q
  __shared__ __align__(16) unsigned short vT_s[128][40];   // V^T [f][j]
  __shared__ __align__(16) unsigned short p_s[32][40];     // bf16 attn P
  __shared__ float sc_s[32 * 33];
  __shared__ float cs[32][4];
  __shared__ float red_s[8][16][2];
  __shared__ float wmax_s[2][128];
  __shared__ float pooled_s[128];

  const int t   = threadIdx.x;
  const int bid = blockIdx.x;
  const int b   = bid >> 9;
  const int g   = bid & 511;
  const int wv = t >> 6, lane = t & 63, quad = lane >> 4, col = lane & 15;

  // ---- stage feats (gather + fp32->bf16): 16 thr/row, 8 elems each ----
  {
    const int p = t >> 4, sg = t & 15;
    const int pid = groups[(b << 14) + g * KP + p];
    const float* src = inputs + ((size_t)(b << 14) + (size_t)pid) * D_ + sg * 8;
    float4 a0 = *(const float4*)(src);
    float4 a1 = *(const float4*)(src + 4);
    uint4 o0;
    o0.x = f2bf(a0.x) | ((unsigned)f2bf(a0.y) << 16);
    o0.y = f2bf(a0.z) | ((unsigned)f2bf(a0.w) << 16);
    o0.z = f2bf(a1.x) | ((unsigned)f2bf(a1.y) << 16);
    o0.w = f2bf(a1.z) | ((unsigned)f2bf(a1.w) << 16);
    *(uint4*)&feats_s[p][sg * 8] = o0;
  }
  if (t < 32) {
    const int pid = groups[(b << 14) + g * KP + t];
    const float* cp = coords + ((size_t)(b << 14) + (size_t)pid) * 3;
    cs[t][0] = cp[0]; cs[t][1] = cp[1]; cs[t][2] = cp[2];
  }
  __syncthreads();

  // ---- per-wave tile assignment for phase A (8 waves) ----
  const int starts[4] = {0, 9, 18, 26};
  const int range = wv >> 1;            // 4 tile ranges (9,9,8,8 tiles)
  const int rt    = wv & 1;             // row half (rows rt*16..rt*16+15)
  const int start = starts[range];
  const int cnt   = (range < 2) ? 9 : 8;

  for (int layer = 0; layer < 2; layer++) {
    const unsigned short (*Asrc)[136] = (layer == 0) ? feats_s : f1_s;
    const uint4* fr = (const uint4*)(allfrag + (size_t)layer * FRAG_S) + lane;
    const float* bcl = bc + layer * 544;

    // Phase A: qkv+dk GEMM, tile-PAIRS with preloaded A-frags (low VGPR).
    uint4 avu[4];
    #pragma unroll
    for (int ks = 0; ks < 4; ks++)
      avu[ks] = *(const uint4*)&Asrc[rt * 16 + col][ks * 32 + quad * 8];

    #pragma unroll
    for (int u0 = 0; u0 < 10; u0 += 2) {
      f32x4 pacc[2];
      pacc[0] = (f32x4){0.f, 0.f, 0.f, 0.f};
      pacc[1] = (f32x4){0.f, 0.f, 0.f, 0.f};
      #pragma unroll
      for (int ks = 0; ks < 4; ks++) {
        short8 av = as_short8(avu[ks]);
        #pragma unroll
        for (int h = 0; h < 2; h++) {
          if (u0 + h < cnt) {
            short8 bv = as_short8(fr[((start + u0 + h) * 4 + ks) * 64]);
            pacc[h] = __builtin_amdgcn_mfma_f32_16x16x32_bf16(av, bv, pacc[h], 0, 0, 0);
          }
        }
      }
      #pragma unroll
      for (int h = 0; h < 2; h++) {
        if (u0 + h < cnt) {
          const int cc = (start + u0 + h) * 16 + col;
          const float bsv = bcl[cc];
          if (cc >= 256 && cc < 384) {          // V tile -> vT_s[f][j], b64
            const unsigned lo = f2bf(pacc[h][0] + bsv)
                              | ((unsigned)f2bf(pacc[h][1] + bsv) << 16);
            const unsigned hi = f2bf(pacc[h][2] + bsv)
                              | ((unsigned)f2bf(pacc[h][3] + bsv) << 16);
            uint2 w = {lo, hi};
            *(uint2*)&vT_s[cc - 256][rt * 16 + quad * 4] = w;
          } else {
            const int ccol = (cc < 256) ? cc : cc - 128;   // dk -> 256..405
            #pragma unroll
            for (int reg = 0; reg < 4; reg++)
              qk_s[rt * 16 + quad * 4 + reg][ccol] = f2bf(pacc[h][reg] + bsv);
          }
        }
      }
    }
    __syncthreads();

    // scores via MFMA from LDS frags (waves 0..3)
    if (wv < 4) {
      const int ihalf = wv >> 1, jhalf = wv & 1;
      f32x4 sacc = {0.f, 0.f, 0.f, 0.f};
      #pragma unroll
      for (int ks = 0; ks < 4; ks++) {
        short8 qv = as_short8(*(const uint4*)&qk_s[ihalf * 16 + col][ks * 32 + quad * 8]);
        short8 kv = as_short8(*(const uint4*)&qk_s[jhalf * 16 + col][128 + ks * 32 + quad * 8]);
        sacc = __builtin_amdgcn_mfma_f32_16x16x32_bf16(qv, kv, sacc, 0, 0, 0);
      }
      const int j = jhalf * 16 + col;
      const float cjx = cs[j][0], cjy = cs[j][1], cjz = cs[j][2];
      #pragma unroll
      for (int reg = 0; reg < 4; reg++) {
        const int i = ihalf * 16 + quad * 4 + reg;
        const float dx = cs[i][0] - cjx;
        const float dy = cs[i][1] - cjy;
        const float dz = cs[i][2] - cjz;
        int ix = (int)floorf((dx + VSF) / QSF);
        int iy = (int)floorf((dy + VSF) / QSF);
        int iz = (int)floorf((dz + VSF) / QSF);
        ix = ix < 0 ? 0 : (ix > 49 ? 49 : ix);
        iy = iy < 0 ? 0 : (iy > 49 ? 49 : iy);
        iz = iz < 0 ? 0 : (iz > 49 ? 49 : iz);
        const unsigned short* dki = &qk_s[i][256];
        const float biasv = bu(dki[ix]) + bu(dki[50 + iy]) + bu(dki[100 + iz]);
        sc_s[i * 33 + j] = (sacc[reg] + biasv) * SCALE;
      }
    }
    __syncthreads();

    // softmax: 8 threads per row (t<256); emit bf16 P
    if (t < 256) {
      const int p = t >> 3, sg = t & 7;
      float vals[4];
      float lm = -1e30f;
      #pragma unroll
      for (int u = 0; u < 4; u++) {
        vals[u] = sc_s[p * 33 + sg + u * 8];
        lm = fmaxf(lm, vals[u]);
      }
      lm = fmaxf(lm, __shfl_xor(lm, 1));
      lm = fmaxf(lm, __shfl_xor(lm, 2));
      lm = fmaxf(lm, __shfl_xor(lm, 4));
      float ls = 0.f;
      #pragma unroll
      for (int u = 0; u < 4; u++) { vals[u] = __expf(vals[u] - lm); ls += vals[u]; }
      ls += __shfl_xor(ls, 1);
      ls += __shfl_xor(ls, 2);
      ls += __shfl_xor(ls, 4);
      const float inv = 1.f / ls;
      #pragma unroll
      for (int u = 0; u < 4; u++)
        p_s[p][sg + u * 8] = f2bf(vals[u] * inv);
    }
    __syncthreads();

    // PV via MFMA: wave wv does mt=wv&1, ftiles (wv>>1)*2 + {0,1}
    {
      const int mt = wv & 1, ftb = (wv >> 1) * 2;
      unsigned short* dst_base = (layer == 0) ? &f1_s[0][0] : &qk_s[0][0];
      const int dst_ld = (layer == 0) ? 136 : 424;
      short8 pv = as_short8(*(const uint4*)&p_s[mt * 16 + col][quad * 8]);
      #pragma unroll
      for (int u = 0; u < 2; u++) {
        const int ft = ftb + u;
        short8 vv = as_short8(*(const uint4*)&vT_s[ft * 16 + col][quad * 8]);
        f32x4 o = (f32x4){0.f, 0.f, 0.f, 0.f};
        o = __builtin_amdgcn_mfma_f32_16x16x32_bf16(pv, vv, o, 0, 0, 0);
        const int f = ft * 16 + col;
        #pragma unroll
        for (int reg = 0; reg < 4; reg++) {
          const int i = mt * 16 + quad * 4 + reg;
          dst_base[i * dst_ld + f] = f2bf(o[reg]);
        }
      }
    }
    __syncthreads();
  }

  // ---- trans GEMM (K=384: feats|f1|f2) + LN + ReLU + maxpool + outputs ----
  const int mtile = wv & 1, colq = wv >> 1;   // 2 ntiles per wave
  f32x4 tacc[2];
  tacc[0] = (f32x4){0.f, 0.f, 0.f, 0.f};
  tacc[1] = (f32x4){0.f, 0.f, 0.f, 0.f};
  const uint4* tf = (const uint4*)transfrag + lane;
  #pragma unroll
  for (int ks = 0; ks < 12; ks++) {
    const unsigned short* ar =
        (ks < 4) ? &feats_s[mtile * 16 + col][(ks & 3) * 32 + quad * 8]
      : (ks < 8) ? &f1_s[mtile * 16 + col][(ks & 3) * 32 + quad * 8]
                 : &qk_s[mtile * 16 + col][(ks & 3) * 32 + quad * 8];  // f2
    short8 av = as_short8(*(const uint4*)ar);
    #pragma unroll
    for (int u = 0; u < 2; u++) {
      const int nt = colq * 2 + u;
      short8 bv = as_short8(tf[(nt * 12 + ks) * 64]);
      tacc[u] = __builtin_amdgcn_mfma_f32_16x16x32_bf16(av, bv, tacc[u], 0, 0, 0);
    }
  }
  // bias + LN partial stats (32 cols per wave)
  float s[4] = {0.f, 0.f, 0.f, 0.f}, ssq[4] = {0.f, 0.f, 0.f, 0.f};
  float gg[2], lb[2];
  #pragma unroll
  for (int u = 0; u < 2; u++) {
    const int c = (colq * 2 + u) * 16 + col;
    const float bsv = trans_b[c];
    gg[u] = ln_g[c]; lb[u] = ln_b[c];
    #pragma unroll
    for (int reg = 0; reg < 4; reg++) {
      const float v = tacc[u][reg] + bsv;
      tacc[u][reg] = v;
      s[reg] += v; ssq[reg] += v * v;
    }
  }
  #pragma unroll
  for (int mk = 1; mk <= 8; mk <<= 1) {
    #pragma unroll
    for (int reg = 0; reg < 4; reg++) {
      s[reg]   += __shfl_xor(s[reg],   mk);
      ssq[reg] += __shfl_xor(ssq[reg], mk);
    }
  }
  if (col == 0) {
    #pragma unroll
    for (int reg = 0; reg < 4; reg++) {
      red_s[wv][quad * 4 + reg][0] = s[reg];
      red_s[wv][quad * 4 + reg][1] = ssq[reg];
    }
  }
  __syncthreads();
  float mu[4], rstd[4];
  #pragma unroll
  for (int reg = 0; reg < 4; reg++) {
    float st = 0.f, sst = 0.f;
    #pragma unroll
    for (int w = 0; w < 4; w++) {
      st  += red_s[mtile + w * 2][quad * 4 + reg][0];
      sst += red_s[mtile + w * 2][quad * 4 + reg][1];
    }
    mu[reg] = st * (1.f / 128.f);
    const float var = sst * (1.f / 128.f) - mu[reg] * mu[reg];
    rstd[reg] = rsqrtf(var + 1e-5f);
  }
  // LN + ReLU + column max over this wave's 16 rows
  float cm[2];
  #pragma unroll
  for (int u = 0; u < 2; u++) {
    float mx = 0.f;   // ReLU floor
    #pragma unroll
    for (int reg = 0; reg < 4; reg++) {
      float v = (tacc[u][reg] - mu[reg]) * rstd[reg] * gg[u] + lb[u];
      v = fmaxf(v, 0.f);
      mx = fmaxf(mx, v);
    }
    cm[u] = mx;
  }
  #pragma unroll
  for (int u = 0; u < 2; u++) {
    cm[u] = fmaxf(cm[u], __shfl_xor(cm[u], 16));
    cm[u] = fmaxf(cm[u], __shfl_xor(cm[u], 32));
  }
  if (quad == 0) {
    #pragma unroll
    for (int u = 0; u < 2; u++)
      wmax_s[mtile][(colq * 2 + u) * 16 + col] = cm[u];
  }
  __syncthreads();

  // pooled = max over both row halves; grid-reordered out write
  if (t < 128) {
    const int c = t;
    const float mx = fmaxf(wmax_s[0][c], wmax_s[1][c]);
    pooled_s[c] = mx;
    const int mm = g >> 6, nn = (g >> 3) & 7, tt2 = g & 7;
    const int opos = tt2 * 64 + nn * 8 + mm;
    out_all[((size_t)b * G_ + opos) * D_ + c] = mx;
  }
  __syncthreads();

  // scatter pooled to every point (for_ret); 256 threads, 16 floats each
  if (t < 256) {
    const int p = t >> 3, sg = t & 7;
    const int pid = groups[(b << 14) + g * KP + p];
    float* dst = out_all + (size_t)BB * G_ * D_
               + ((size_t)(b << 14) + (size_t)pid) * D_ + sg * 16;
    #pragma unroll
    for (int u = 0; u < 4; u++)
      *(float4*)(dst + u * 4) = *(const float4*)&pooled_s[sg * 16 + u * 4];
  }
}

// ---------------------------------------------------------------------------
extern "C" void kernel_launch(void* const* d_in, const int* in_sizes, int n_in,
                              void* d_out, int out_size, void* d_ws, size_t ws_size,
                              hipStream_t stream) {
  const float* inputs  = (const float*)d_in[0];
  const float* coords  = (const float*)d_in[1];
  const float* qkv_w   = (const float*)d_in[2];   // [2,128,384]
  const float* qkv_b   = (const float*)d_in[3];   // [2,384]
  const float* tbl_x   = (const float*)d_in[4];   // [2,3,50,128]
  const float* tbl_y   = (const float*)d_in[5];
  const float* tbl_z   = (const float*)d_in[6];
  const float* trans_w = (const float*)d_in[7];   // [384,128]
  const float* trans_b = (const float*)d_in[8];
  const float* ln_g    = (const float*)d_in[9];
  const float* ln_b    = (const float*)d_in[10];
  const int*   groups  = (const int*)d_in[11];    // [2,512,32] flat

  float* out = (float*)d_out;
  unsigned short* allfrag   = (unsigned short*)d_ws;       // 2*FRAG_S
  unsigned short* transfrag = allfrag + 2 * FRAG_S;        // 96*512
  float* Tt  = (float*)(transfrag + 96 * 512);             // 2*128*256 f32
  float* Wf  = Tt + (size_t)2 * 128 * 256;                 // 2*128*256 f32
  float* bc  = Wf + (size_t)2 * 128 * 256;                 // 2*544 f32

  // ---- prep (weights only) ----
  prep_tt<<<256, 256, 0, stream>>>(tbl_x, tbl_y, tbl_z, Tt);
  wf_gemm<<<dim3(2, 2, 2), 256, 0, stream>>>(qkv_w, Tt, Wf);
  pack2<<<370, 64, 0, stream>>>(qkv_w, Wf, trans_w, qkv_b, Tt,
                                allfrag, transfrag, bc);

  // ---- whole network, one kernel ----
  mega<<<BB * G_, 512, 0, stream>>>(inputs, coords, groups, allfrag, bc,
                                    transfrag, trans_b, ln_g, ln_b, out);
}